// Round 12
// baseline (275.738 us; speedup 1.0000x reference)
//
#include <hip/hip_runtime.h>
#include <hip/hip_bf16.h>
#include <stdint.h>

#define Sx 2048
#define Ex 1024
#define Hx 16
#define Dx 64

typedef __attribute__((ext_vector_type(8))) short short8;
typedef __attribute__((ext_vector_type(4))) short bh4;
typedef __attribute__((ext_vector_type(4))) float f32x4;
typedef __attribute__((ext_vector_type(2))) unsigned int u32x2;

// fp32 -> bf16 bits, round-to-nearest-even
__device__ inline short f2bf(float f) {
    unsigned u = __builtin_bit_cast(unsigned, f);
    u = (u + 0x7fffu + ((u >> 16) & 1u)) >> 16;
    return (short)u;
}

// packed pair fp32 -> 2x bf16 in one u32 (lo = a, hi = b)
__device__ inline unsigned cvtpk_bf16(float a, float b) {
    unsigned r;
    asm("v_cvt_pk_bf16_f32 %0, %1, %2" : "=v"(r) : "v"(a), "v"(b));
    return r;
}

// fast 2^x (v_exp_f32)
__device__ inline float exp2fast(float x) { return __builtin_amdgcn_exp2f(x); }

// async global->LDS, 16B per lane; LDS base wave-uniform, HW adds lane*16.
__device__ inline void gload16(const short* g, short* l) {
    __builtin_amdgcn_global_load_lds((const __attribute__((address_space(1))) void*)g,
                                     (__attribute__((address_space(3))) void*)l, 16, 0, 0);
}

// ---------------------------------------------------------------------------
// prep: convert the 3 activations + 4 weights fp32 -> bf16 into ws
// ---------------------------------------------------------------------------
__global__ __launch_bounds__(256) void prep(const float* __restrict__ q,
                                            const float* __restrict__ k,
                                            const float* __restrict__ v,
                                            const float* __restrict__ wq,
                                            const float* __restrict__ wk,
                                            const float* __restrict__ wv_,
                                            const float* __restrict__ wo,
                                            short* __restrict__ ws) {
    const int seg = blockIdx.y;
    const float* src; size_t n, doff;
    switch (seg) {
        case 0: src = q;   n = 4194304; doff = 0;        break;
        case 1: src = k;   n = 4194304; doff = 4194304;  break;
        case 2: src = v;   n = 4194304; doff = 8388608;  break;
        case 3: src = wq;  n = 1048576; doff = 12582912; break;
        case 4: src = wk;  n = 1048576; doff = 13631488; break;
        case 5: src = wv_; n = 1048576; doff = 14680064; break;
        default: src = wo; n = 1048576; doff = 15728640; break;
    }
    short* dst = ws + doff;
    for (size_t i = ((size_t)blockIdx.x * 256 + threadIdx.x) * 8; i < n;
         i += (size_t)gridDim.x * 256 * 8) {
        float4 f0 = *(const float4*)&src[i];
        float4 f1 = *(const float4*)&src[i + 4];
        short8 s;
        s[0]=f2bf(f0.x); s[1]=f2bf(f0.y); s[2]=f2bf(f0.z); s[3]=f2bf(f0.w);
        s[4]=f2bf(f1.x); s[5]=f2bf(f1.y); s[6]=f2bf(f1.z); s[7]=f2bf(f1.w);
        *(short8*)&dst[i] = s;
    }
}

// ---------------------------------------------------------------------------
// Merged QKV projection: grid.z selects (X, W, bias, out, mode).
// z=0,1: qhat/khat [b,s,e] bf16 (D transposed). z=2: vT [b,h,d,s] bf16.
// ---------------------------------------------------------------------------
__global__ __launch_bounds__(256) void gemm_qkv3(const short* __restrict__ wsb,
                                                 const float* __restrict__ bq,
                                                 const float* __restrict__ bk,
                                                 const float* __restrict__ bv,
                                                 short* __restrict__ qh,
                                                 short* __restrict__ kh,
                                                 short* __restrict__ vt) {
    __shared__ short wt[128 * 64];
    __shared__ short xt[128 * 64];
    const int z = blockIdx.z;
    const short* X  = wsb + (size_t)z * 4194304;
    const short* Wm = wsb + 12582912 + (size_t)z * 1048576;
    const float* bias = (z == 0) ? bq : (z == 1) ? bk : bv;
    short* outb = (z == 0) ? qh : (z == 1) ? kh : vt;
    const bool vmode = (z == 2);

    const int tid = threadIdx.x;
    const int l = tid & 63, wv = tid >> 6;
    const int r15 = l & 15, g = l >> 4;
    const int wm = wv >> 1, wn = wv & 1;
    const int i0 = blockIdx.x << 7;
    const int j0 = blockIdx.y << 7;
    const int lrow = l >> 3, lgi = l & 7;

    f32x4 acc[4][4] = {};

    for (int k0 = 0; k0 < Ex; k0 += 64) {
        __syncthreads();
        #pragma unroll
        for (int p = 0; p < 4; ++p) {
            int row = p * 32 + wv * 8 + lrow;
            int col = ((lgi ^ (row & 7)) << 3) + k0;
            gload16(&Wm[(size_t)(j0 + row) * Ex + col], &wt[(p * 32 + wv * 8) * 64]);
            gload16(&X [(size_t)(i0 + row) * Ex + col], &xt[(p * 32 + wv * 8) * 64]);
        }
        __syncthreads();
        const short* At = vmode ? xt : wt;
        const short* Bt = vmode ? wt : xt;
        #pragma unroll
        for (int kk = 0; kk < 64; kk += 32) {
            const int sw = (((kk >> 3) + g) ^ (r15 & 7)) << 3;
            short8 a[4], b[4];
            #pragma unroll
            for (int m = 0; m < 4; ++m)
                a[m] = *(const short8*)&At[(wm * 64 + m * 16 + r15) * 64 + sw];
            #pragma unroll
            for (int n = 0; n < 4; ++n)
                b[n] = *(const short8*)&Bt[(wn * 64 + n * 16 + r15) * 64 + sw];
            #pragma unroll
            for (int m = 0; m < 4; ++m)
                #pragma unroll
                for (int n = 0; n < 4; ++n)
                    acc[m][n] = __builtin_amdgcn_mfma_f32_16x16x32_bf16(a[m], b[n], acc[m][n], 0, 0, 0);
        }
    }

    if (!vmode) {              // D[j][i]; rows j 4-contig per lane
        #pragma unroll
        for (int m = 0; m < 4; ++m) {
            int jb = j0 + wm * 64 + m * 16 + (g << 2);
            float4 bvv = *(const float4*)&bias[jb];
            #pragma unroll
            for (int n = 0; n < 4; ++n) {
                int i = i0 + wn * 64 + n * 16 + r15;
                bh4 s;
                s[0] = f2bf(acc[m][n][0] + bvv.x);
                s[1] = f2bf(acc[m][n][1] + bvv.y);
                s[2] = f2bf(acc[m][n][2] + bvv.z);
                s[3] = f2bf(acc[m][n][3] + bvv.w);
                *(bh4*)&outb[(size_t)i * Ex + jb] = s;
            }
        }
    } else {                   // D[i][j]; rows i 4-contig -> vT[b,h,d,s]
        #pragma unroll
        for (int m = 0; m < 4; ++m) {
            int ib = i0 + wm * 64 + m * 16 + (g << 2);
            int b_ = ib >> 11, s0 = ib & 2047;
            #pragma unroll
            for (int n = 0; n < 4; ++n) {
                int j = j0 + wn * 64 + n * 16 + r15;
                float bj = bias[j];
                bh4 s;
                s[0] = f2bf(acc[m][n][0] + bj);
                s[1] = f2bf(acc[m][n][1] + bj);
                s[2] = f2bf(acc[m][n][2] + bj);
                s[3] = f2bf(acc[m][n][3] + bj);
                *(bh4*)&outb[((size_t)(b_ * Hx + (j >> 6)) * Dx + (j & 63)) * Sx + s0] = s;
            }
        }
    }
}

// ---------------------------------------------------------------------------
// Output projection: fp32 out = Xb(bf16) @ W^T + bias. 2-phase LDS dbuf.
// ---------------------------------------------------------------------------
__global__ __launch_bounds__(256) void gemm_out(const short* __restrict__ Xb,
                                                const short* __restrict__ Wb,
                                                const float* __restrict__ bias,
                                                float* __restrict__ out) {
    __shared__ short wt[2][128 * 64];
    __shared__ short xt[2][128 * 64];
    const int tid = threadIdx.x;
    const int l = tid & 63, wv = tid >> 6;
    const int r15 = l & 15, g = l >> 4;
    const int wm = wv >> 1, wn = wv & 1;
    const int i0 = blockIdx.x << 7;
    const int j0 = blockIdx.y << 7;
    const int lrow = l >> 3, lgi = l & 7;

    f32x4 acc[4][4] = {};

    auto stage = [&](int it, int buf) {
        int k0 = it << 6;
        #pragma unroll
        for (int p = 0; p < 4; ++p) {
            int row = p * 32 + wv * 8 + lrow;
            int col = ((lgi ^ (row & 7)) << 3) + k0;
            gload16(&Wb[(size_t)(j0 + row) * Ex + col], &wt[buf][(p * 32 + wv * 8) * 64]);
            gload16(&Xb[(size_t)(i0 + row) * Ex + col], &xt[buf][(p * 32 + wv * 8) * 64]);
        }
    };

    stage(0, 0);
    for (int it = 0; it < 16; ++it) {
        __syncthreads();
        if (it + 1 < 16) stage(it + 1, (it + 1) & 1);
        const int cur = it & 1;
        #pragma unroll
        for (int kk = 0; kk < 64; kk += 32) {
            const int sw = (((kk >> 3) + g) ^ (r15 & 7)) << 3;
            short8 a[4], b[4];
            #pragma unroll
            for (int m = 0; m < 4; ++m)
                a[m] = *(const short8*)&wt[cur][(wm * 64 + m * 16 + r15) * 64 + sw];
            #pragma unroll
            for (int n = 0; n < 4; ++n)
                b[n] = *(const short8*)&xt[cur][(wn * 64 + n * 16 + r15) * 64 + sw];
            #pragma unroll
            for (int m = 0; m < 4; ++m)
                #pragma unroll
                for (int n = 0; n < 4; ++n)
                    acc[m][n] = __builtin_amdgcn_mfma_f32_16x16x32_bf16(a[m], b[n], acc[m][n], 0, 0, 0);
        }
    }

    #pragma unroll
    for (int m = 0; m < 4; ++m) {
        int jb = j0 + wm * 64 + m * 16 + (g << 2);
        float4 bvv = *(const float4*)&bias[jb];
        #pragma unroll
        for (int n = 0; n < 4; ++n) {
            int i = i0 + wn * 64 + n * 16 + r15;
            float4 o;
            o.x = acc[m][n][0] + bvv.x;
            o.y = acc[m][n][1] + bvv.y;
            o.z = acc[m][n][2] + bvv.z;
            o.w = acc[m][n][3] + bvv.w;
            *(float4*)&out[(size_t)i * Ex + jb] = o;
        }
    }
}

// ---------------------------------------------------------------------------
// Fused causal attention — R11 8-wave structure + pass-1 3-buffer pipeline
// with counted vmcnt + raw barrier (T3/T4): stage(kt+2) in flight across the
// barrier, wait vmcnt(1) steady / vmcnt(0) last tile. Pass 1 has no stores,
// so vmcnt counts only the K gload_lds ops. Pass 2 unchanged (plain
// __syncthreads; its nt-stores would pollute counted vmcnt).
// ---------------------------------------------------------------------------
__global__ void attn_fused(const short* __restrict__ qhat,
                           const short* __restrict__ khat,
                           const short* __restrict__ vT,
                           const float* __restrict__ table,
                           float* __restrict__ attn,
                           short* __restrict__ om) {
    __shared__ short ks[3][64 * 64];
    __shared__ short vs[3][64 * 64];
    __shared__ short ps[128 * 64];
    __shared__ float bl[1028];

    const int tid = threadIdx.x;
    const int l = tid & 63, wv = tid >> 6;       // wv in [0,8)
    const int r15 = l & 15, g = l >> 4;

    // block swizzle: same-bh blocks on one XCD; co-resident pairs (qt,15-qt)
    const int lin = blockIdx.x + (blockIdx.y << 4);
    const int xcd = lin & 7, slot = lin >> 3;
    const int bh = xcd + ((slot & 3) << 3);
    const int qidx = (slot >> 2) & 7;
    const int qt = (slot >> 5) ? (15 - qidx) : qidx;

    const int b = bh >> 4, h = bh & 15;
    const int lrow = l >> 3, lgi = l & 7;
    const int nkt = 2 * qt + 2;
    const float cs2 = 0.18033688f;   // 0.125 * log2(e)

    for (int i = tid; i < 1025; i += 512)
        bl[i] = (i < 512) ? -3e30f : (table[i * Hx + h] - 16.0f) * 1.4426950408889634f;

    // Q fragments in registers: wave owns q rows [qt*128 + wv*16, +16)
    short8 qf[2];
    {
        const size_t qrow = (size_t)(b * Sx + (qt << 7) + wv * 16 + r15);
        #pragma unroll
        for (int kk = 0; kk < 2; ++kk)
            qf[kk] = *(const short8*)&qhat[qrow * Ex + h * Dx + kk * 32 + g * 8];
    }

    // staging: wave wv stages rows [wv*8, wv*8+8) of the 64-row tile (1 load)
    auto stageK = [&](int kt, int buf) {
        int row = wv * 8 + lrow;
        gload16(&khat[(size_t)(b * Sx + (kt << 6) + row) * Ex + h * Dx + ((lgi ^ (row & 7)) << 3)],
                &ks[buf][(wv * 8) * 64]);
    };
    auto stageV = [&](int kt, int buf) {
        int row = wv * 8 + lrow;
        gload16(&vT[((size_t)bh * Dx + row) * Sx + (kt << 6) + ((lgi ^ (row & 7)) << 3)],
                &vs[buf][(wv * 8) * 64]);
    };

    float sr = 0.f;
    const int qg0 = (qt << 7) + wv * 16 + r15;

    // ---- pass 1: 3-buf counted-vmcnt pipeline ----
    stageK(0, 0);
    if (nkt > 1) stageK(1, 1);
    __syncthreads();                 // full drain: bl init + stage(0) visible
    for (int kt = 0; kt < nkt; ++kt) {
        if (kt) {
            // need stage(kt) drained; stage(kt+1) (1 load/wave) may stay in
            // flight. Last tile: nothing newer -> drain all.
            if (kt + 1 < nkt) asm volatile("s_waitcnt vmcnt(1)" ::: "memory");
            else              asm volatile("s_waitcnt vmcnt(0)" ::: "memory");
            __builtin_amdgcn_s_barrier();
            __builtin_amdgcn_sched_barrier(0);
        }
        if (kt + 2 < nkt) stageK(kt + 2, (kt + 2) % 3);
        const short* kb = ks[kt % 3];
        f32x4 sf[4] = {};
        __builtin_amdgcn_s_setprio(1);
        #pragma unroll
        for (int kk = 0; kk < 64; kk += 32) {
            const int sw = (((kk >> 3) + g) ^ (r15 & 7)) << 3;
            short8 a[4];
            #pragma unroll
            for (int m = 0; m < 4; ++m) a[m] = *(const short8*)&kb[(m * 16 + r15) * 64 + sw];
            #pragma unroll
            for (int m = 0; m < 4; ++m)
                sf[m] = __builtin_amdgcn_mfma_f32_16x16x32_bf16(a[m], qf[kk >> 5], sf[m], 0, 0, 0);
        }
        __builtin_amdgcn_s_setprio(0);
        const int kcb = (kt << 6) + (g << 2);
        int base = qg0 + 512 - kcb;
        float psum = 0.f;
        #pragma unroll
        for (int m = 0; m < 4; ++m) {
            int b0 = base - m * 16;
            #pragma unroll
            for (int r = 0; r < 4; ++r) {
                int idx = b0 - r;            // >= 385 always
                idx = idx > 1024 ? 1024 : idx;
                psum += exp2fast(fmaf(sf[m][r], cs2, bl[idx]));
            }
        }
        psum += __shfl_xor(psum, 16);
        psum += __shfl_xor(psum, 32);
        sr += psum;
    }

    const float inv = 1.0f / sr;
    f32x4 of[4] = {};
    float* Ap = attn + (size_t)bh * ((size_t)Sx * Sx);

    // ---- pass 2: recompute, write normalized attn (nt), O^T = V^T @ P ----
    __syncthreads();
    stageK(0, 0);
    stageV(0, 0);
    for (int kt = 0; kt < nkt; ++kt) {
        __syncthreads();
        if (kt + 1 < nkt) { stageK(kt + 1, (kt + 1) % 3); stageV(kt + 1, (kt + 1) % 3); }
        const int cur = kt % 3;
        f32x4 sf[4] = {};
        __builtin_amdgcn_s_setprio(1);
        #pragma unroll
        for (int kk = 0; kk < 64; kk += 32) {
            const int sw = (((kk >> 3) + g) ^ (r15 & 7)) << 3;
            short8 a[4];
            #pragma unroll
            for (int m = 0; m < 4; ++m) a[m] = *(const short8*)&ks[cur][(m * 16 + r15) * 64 + sw];
            #pragma unroll
            for (int m = 0; m < 4; ++m)
                sf[m] = __builtin_amdgcn_mfma_f32_16x16x32_bf16(a[m], qf[kk >> 5], sf[m], 0, 0, 0);
        }
        __builtin_amdgcn_s_setprio(0);
        {
            const int q = qg0;
            const int qrow = wv * 16 + r15;
            #pragma unroll
            for (int m = 0; m < 4; ++m) {
                int kc0 = (kt << 6) + m * 16 + (g << 2);
                int b0 = q + 512 - kc0;
                f32x4 pv;
                #pragma unroll
                for (int r = 0; r < 4; ++r) {
                    int idx = b0 - r;
                    idx = idx > 1024 ? 1024 : idx;
                    pv[r] = exp2fast(fmaf(sf[m][r], cs2, bl[idx])) * inv;
                }
                __builtin_nontemporal_store(pv, (f32x4*)&Ap[(size_t)q * Sx + kc0]);
                u32x2 pk;
                pk[0] = cvtpk_bf16(pv[0], pv[1]);
                pk[1] = cvtpk_bf16(pv[2], pv[3]);
                int gphys = (m * 2 + (g >> 1)) ^ (r15 & 7);
                *(u32x2*)&ps[qrow * 64 + gphys * 8 + (g & 1) * 4] = pk;
            }
        }
        // ps rows are wave-private: no barrier needed (lgkmcnt RAW only)
        __builtin_amdgcn_s_setprio(1);
        #pragma unroll
        for (int kk = 0; kk < 64; kk += 32) {
            const int sw = (((kk >> 3) + g) ^ (r15 & 7)) << 3;
            short8 a[4], bp;
            #pragma unroll
            for (int m = 0; m < 4; ++m) a[m] = *(const short8*)&vs[cur][(m * 16 + r15) * 64 + sw];
            bp = *(const short8*)&ps[(wv * 16 + r15) * 64 + sw];
            #pragma unroll
            for (int m = 0; m < 4; ++m)
                of[m] = __builtin_amdgcn_mfma_f32_16x16x32_bf16(a[m], bp, of[m], 0, 0, 0);
        }
        __builtin_amdgcn_s_setprio(0);
    }

    // O^T C-layout: col = q (r15), rows = d 4-contig -> 8B stores
    {
        const int qv = (qt << 7) + wv * 16 + r15;
        #pragma unroll
        for (int m = 0; m < 4; ++m) {
            int d0 = m * 16 + (g << 2);
            u32x2 s;
            s[0] = cvtpk_bf16(of[m][0], of[m][1]);
            s[1] = cvtpk_bf16(of[m][2], of[m][3]);
            *(u32x2*)&om[(size_t)(b * Sx + qv) * Ex + h * Dx + d0] = s;
        }
    }

    // zero-fill fully masked region (nontemporal), 512 threads
    const int c0 = nkt << 6;
    f32x4 z = {0.f, 0.f, 0.f, 0.f};
    for (int row = tid >> 3; row < 128; row += 64) {
        size_t base = (size_t)((qt << 7) + row) * Sx;
        for (int c = c0 + ((tid & 7) << 2); c < Sx; c += 32)
            __builtin_nontemporal_store(z, (f32x4*)&Ap[base + c]);
    }
}

extern "C" void kernel_launch(void* const* d_in, const int* in_sizes, int n_in,
                              void* d_out, int out_size, void* d_ws, size_t ws_size,
                              hipStream_t stream) {
    const float* query = (const float*)d_in[0];
    const float* key   = (const float*)d_in[1];
    const float* value = (const float*)d_in[2];
    const float* bq = (const float*)d_in[4];
    const float* bk = (const float*)d_in[6];
    const float* bv = (const float*)d_in[8];
    const float* bo = (const float*)d_in[10];
    const float* Wq = (const float*)d_in[3];
    const float* Wk = (const float*)d_in[5];
    const float* Wv = (const float*)d_in[7];
    const float* Wo = (const float*)d_in[9];
    const float* tbl = (const float*)d_in[11];

    short* ws = (short*)d_ws;
    short* qx  = ws;                    // query bf16; later reused as O (bf16)
    short* wob = ws + 15728640;
    short* qh  = ws + 16777216;
    short* kh  = ws + 20971520;
    short* vt  = ws + 25165824;

    float* outp  = (float*)d_out;
    float* attnp = outp + 4194304;

    prep<<<dim3(1024, 7), 256, 0, stream>>>(query, key, value, Wq, Wk, Wv, Wo, ws);
    gemm_qkv3<<<dim3(32, 8, 3), 256, 0, stream>>>(ws, bq, bk, bv, qh, kh, vt);
    attn_fused<<<dim3(16, 32), 512, 0, stream>>>(qh, kh, vt, tbl, attnp, qx);
    gemm_out<<<dim3(32, 8), 256, 0, stream>>>(qx, wob, bo, outp);
}

// Round 13
// 274.930 us; speedup vs baseline: 1.0029x; 1.0029x over previous
//
#include <hip/hip_runtime.h>
#include <hip/hip_bf16.h>
#include <stdint.h>

#define Sx 2048
#define Ex 1024
#define Hx 16
#define Dx 64

typedef __attribute__((ext_vector_type(8))) short short8;
typedef __attribute__((ext_vector_type(4))) short bh4;
typedef __attribute__((ext_vector_type(4))) float f32x4;
typedef __attribute__((ext_vector_type(2))) unsigned int u32x2;

// fp32 -> bf16 bits, round-to-nearest-even
__device__ inline short f2bf(float f) {
    unsigned u = __builtin_bit_cast(unsigned, f);
    u = (u + 0x7fffu + ((u >> 16) & 1u)) >> 16;
    return (short)u;
}

// packed pair fp32 -> 2x bf16 in one u32 (lo = a, hi = b)
__device__ inline unsigned cvtpk_bf16(float a, float b) {
    unsigned r;
    asm("v_cvt_pk_bf16_f32 %0, %1, %2" : "=v"(r) : "v"(a), "v"(b));
    return r;
}

// fast 2^x (v_exp_f32)
__device__ inline float exp2fast(float x) { return __builtin_amdgcn_exp2f(x); }

// async global->LDS, 16B per lane; LDS base wave-uniform, HW adds lane*16.
__device__ inline void gload16(const short* g, short* l) {
    __builtin_amdgcn_global_load_lds((const __attribute__((address_space(1))) void*)g,
                                     (__attribute__((address_space(3))) void*)l, 16, 0, 0);
}

// ---------------------------------------------------------------------------
// prep: convert the 3 activations + 4 weights fp32 -> bf16 into ws
// ---------------------------------------------------------------------------
__global__ __launch_bounds__(256) void prep(const float* __restrict__ q,
                                            const float* __restrict__ k,
                                            const float* __restrict__ v,
                                            const float* __restrict__ wq,
                                            const float* __restrict__ wk,
                                            const float* __restrict__ wv_,
                                            const float* __restrict__ wo,
                                            short* __restrict__ ws) {
    const int seg = blockIdx.y;
    const float* src; size_t n, doff;
    switch (seg) {
        case 0: src = q;   n = 4194304; doff = 0;        break;
        case 1: src = k;   n = 4194304; doff = 4194304;  break;
        case 2: src = v;   n = 4194304; doff = 8388608;  break;
        case 3: src = wq;  n = 1048576; doff = 12582912; break;
        case 4: src = wk;  n = 1048576; doff = 13631488; break;
        case 5: src = wv_; n = 1048576; doff = 14680064; break;
        default: src = wo; n = 1048576; doff = 15728640; break;
    }
    short* dst = ws + doff;
    for (size_t i = ((size_t)blockIdx.x * 256 + threadIdx.x) * 8; i < n;
         i += (size_t)gridDim.x * 256 * 8) {
        float4 f0 = *(const float4*)&src[i];
        float4 f1 = *(const float4*)&src[i + 4];
        short8 s;
        s[0]=f2bf(f0.x); s[1]=f2bf(f0.y); s[2]=f2bf(f0.z); s[3]=f2bf(f0.w);
        s[4]=f2bf(f1.x); s[5]=f2bf(f1.y); s[6]=f2bf(f1.z); s[7]=f2bf(f1.w);
        *(short8*)&dst[i] = s;
    }
}

// ---------------------------------------------------------------------------
// Merged QKV projection: grid.z selects (X, W, bias, out, mode).
// z=0,1: qhat/khat [b,s,e] bf16 (D transposed). z=2: vT [b,h,d,s] bf16.
// ---------------------------------------------------------------------------
__global__ __launch_bounds__(256) void gemm_qkv3(const short* __restrict__ wsb,
                                                 const float* __restrict__ bq,
                                                 const float* __restrict__ bk,
                                                 const float* __restrict__ bv,
                                                 short* __restrict__ qh,
                                                 short* __restrict__ kh,
                                                 short* __restrict__ vt) {
    __shared__ short wt[128 * 64];
    __shared__ short xt[128 * 64];
    const int z = blockIdx.z;
    const short* X  = wsb + (size_t)z * 4194304;
    const short* Wm = wsb + 12582912 + (size_t)z * 1048576;
    const float* bias = (z == 0) ? bq : (z == 1) ? bk : bv;
    short* outb = (z == 0) ? qh : (z == 1) ? kh : vt;
    const bool vmode = (z == 2);

    const int tid = threadIdx.x;
    const int l = tid & 63, wv = tid >> 6;
    const int r15 = l & 15, g = l >> 4;
    const int wm = wv >> 1, wn = wv & 1;
    const int i0 = blockIdx.x << 7;
    const int j0 = blockIdx.y << 7;
    const int lrow = l >> 3, lgi = l & 7;

    f32x4 acc[4][4] = {};

    for (int k0 = 0; k0 < Ex; k0 += 64) {
        __syncthreads();
        #pragma unroll
        for (int p = 0; p < 4; ++p) {
            int row = p * 32 + wv * 8 + lrow;
            int col = ((lgi ^ (row & 7)) << 3) + k0;
            gload16(&Wm[(size_t)(j0 + row) * Ex + col], &wt[(p * 32 + wv * 8) * 64]);
            gload16(&X [(size_t)(i0 + row) * Ex + col], &xt[(p * 32 + wv * 8) * 64]);
        }
        __syncthreads();
        const short* At = vmode ? xt : wt;
        const short* Bt = vmode ? wt : xt;
        #pragma unroll
        for (int kk = 0; kk < 64; kk += 32) {
            const int sw = (((kk >> 3) + g) ^ (r15 & 7)) << 3;
            short8 a[4], b[4];
            #pragma unroll
            for (int m = 0; m < 4; ++m)
                a[m] = *(const short8*)&At[(wm * 64 + m * 16 + r15) * 64 + sw];
            #pragma unroll
            for (int n = 0; n < 4; ++n)
                b[n] = *(const short8*)&Bt[(wn * 64 + n * 16 + r15) * 64 + sw];
            #pragma unroll
            for (int m = 0; m < 4; ++m)
                #pragma unroll
                for (int n = 0; n < 4; ++n)
                    acc[m][n] = __builtin_amdgcn_mfma_f32_16x16x32_bf16(a[m], b[n], acc[m][n], 0, 0, 0);
        }
    }

    if (!vmode) {              // D[j][i]; rows j 4-contig per lane
        #pragma unroll
        for (int m = 0; m < 4; ++m) {
            int jb = j0 + wm * 64 + m * 16 + (g << 2);
            float4 bvv = *(const float4*)&bias[jb];
            #pragma unroll
            for (int n = 0; n < 4; ++n) {
                int i = i0 + wn * 64 + n * 16 + r15;
                bh4 s;
                s[0] = f2bf(acc[m][n][0] + bvv.x);
                s[1] = f2bf(acc[m][n][1] + bvv.y);
                s[2] = f2bf(acc[m][n][2] + bvv.z);
                s[3] = f2bf(acc[m][n][3] + bvv.w);
                *(bh4*)&outb[(size_t)i * Ex + jb] = s;
            }
        }
    } else {                   // D[i][j]; rows i 4-contig -> vT[b,h,d,s]
        #pragma unroll
        for (int m = 0; m < 4; ++m) {
            int ib = i0 + wm * 64 + m * 16 + (g << 2);
            int b_ = ib >> 11, s0 = ib & 2047;
            #pragma unroll
            for (int n = 0; n < 4; ++n) {
                int j = j0 + wn * 64 + n * 16 + r15;
                float bj = bias[j];
                bh4 s;
                s[0] = f2bf(acc[m][n][0] + bj);
                s[1] = f2bf(acc[m][n][1] + bj);
                s[2] = f2bf(acc[m][n][2] + bj);
                s[3] = f2bf(acc[m][n][3] + bj);
                *(bh4*)&outb[((size_t)(b_ * Hx + (j >> 6)) * Dx + (j & 63)) * Sx + s0] = s;
            }
        }
    }
}

// ---------------------------------------------------------------------------
// Output projection: fp32 out = Xb(bf16) @ W^T + bias. 2-phase LDS dbuf.
// ---------------------------------------------------------------------------
__global__ __launch_bounds__(256) void gemm_out(const short* __restrict__ Xb,
                                                const short* __restrict__ Wb,
                                                const float* __restrict__ bias,
                                                float* __restrict__ out) {
    __shared__ short wt[2][128 * 64];
    __shared__ short xt[2][128 * 64];
    const int tid = threadIdx.x;
    const int l = tid & 63, wv = tid >> 6;
    const int r15 = l & 15, g = l >> 4;
    const int wm = wv >> 1, wn = wv & 1;
    const int i0 = blockIdx.x << 7;
    const int j0 = blockIdx.y << 7;
    const int lrow = l >> 3, lgi = l & 7;

    f32x4 acc[4][4] = {};

    auto stage = [&](int it, int buf) {
        int k0 = it << 6;
        #pragma unroll
        for (int p = 0; p < 4; ++p) {
            int row = p * 32 + wv * 8 + lrow;
            int col = ((lgi ^ (row & 7)) << 3) + k0;
            gload16(&Wb[(size_t)(j0 + row) * Ex + col], &wt[buf][(p * 32 + wv * 8) * 64]);
            gload16(&Xb[(size_t)(i0 + row) * Ex + col], &xt[buf][(p * 32 + wv * 8) * 64]);
        }
    };

    stage(0, 0);
    for (int it = 0; it < 16; ++it) {
        __syncthreads();
        if (it + 1 < 16) stage(it + 1, (it + 1) & 1);
        const int cur = it & 1;
        #pragma unroll
        for (int kk = 0; kk < 64; kk += 32) {
            const int sw = (((kk >> 3) + g) ^ (r15 & 7)) << 3;
            short8 a[4], b[4];
            #pragma unroll
            for (int m = 0; m < 4; ++m)
                a[m] = *(const short8*)&wt[cur][(wm * 64 + m * 16 + r15) * 64 + sw];
            #pragma unroll
            for (int n = 0; n < 4; ++n)
                b[n] = *(const short8*)&xt[cur][(wn * 64 + n * 16 + r15) * 64 + sw];
            #pragma unroll
            for (int m = 0; m < 4; ++m)
                #pragma unroll
                for (int n = 0; n < 4; ++n)
                    acc[m][n] = __builtin_amdgcn_mfma_f32_16x16x32_bf16(a[m], b[n], acc[m][n], 0, 0, 0);
        }
    }

    #pragma unroll
    for (int m = 0; m < 4; ++m) {
        int jb = j0 + wm * 64 + m * 16 + (g << 2);
        float4 bvv = *(const float4*)&bias[jb];
        #pragma unroll
        for (int n = 0; n < 4; ++n) {
            int i = i0 + wn * 64 + n * 16 + r15;
            float4 o;
            o.x = acc[m][n][0] + bvv.x;
            o.y = acc[m][n][1] + bvv.y;
            o.z = acc[m][n][2] + bvv.z;
            o.w = acc[m][n][3] + bvv.w;
            *(float4*)&out[(size_t)i * Ex + jb] = o;
        }
    }
}

// ---------------------------------------------------------------------------
// Fused causal attention — 8-wave blocks; BOTH passes now use counted-vmcnt
// + raw barrier (T3/T4). Pass 2 never drains its nt P-stores: per-wave vmem
// ops/tile = 2 stage + 4 stores; at top of iter kt each wave waits only for
// its own stage(kt): allowed-in-flight = stores(kt-2)[4] + stage(kt+1)[2] +
// stores(kt-1)[4] -> vmcnt(10) steady (6/8/4 at edges). Wait precedes the
// barrier, so post-barrier all waves' staged rows are valid.
// ---------------------------------------------------------------------------
__global__ void attn_fused(const short* __restrict__ qhat,
                           const short* __restrict__ khat,
                           const short* __restrict__ vT,
                           const float* __restrict__ table,
                           float* __restrict__ attn,
                           short* __restrict__ om) {
    __shared__ short ks[3][64 * 64];
    __shared__ short vs[3][64 * 64];
    __shared__ short ps[128 * 64];
    __shared__ float bl[1028];

    const int tid = threadIdx.x;
    const int l = tid & 63, wv = tid >> 6;       // wv in [0,8)
    const int r15 = l & 15, g = l >> 4;

    // block swizzle: same-bh blocks on one XCD; co-resident pairs (qt,15-qt)
    const int lin = blockIdx.x + (blockIdx.y << 4);
    const int xcd = lin & 7, slot = lin >> 3;
    const int bh = xcd + ((slot & 3) << 3);
    const int qidx = (slot >> 2) & 7;
    const int qt = (slot >> 5) ? (15 - qidx) : qidx;

    const int b = bh >> 4, h = bh & 15;
    const int lrow = l >> 3, lgi = l & 7;
    const int nkt = 2 * qt + 2;
    const float cs2 = 0.18033688f;   // 0.125 * log2(e)

    for (int i = tid; i < 1025; i += 512)
        bl[i] = (i < 512) ? -3e30f : (table[i * Hx + h] - 16.0f) * 1.4426950408889634f;

    // Q fragments in registers: wave owns q rows [qt*128 + wv*16, +16)
    short8 qf[2];
    {
        const size_t qrow = (size_t)(b * Sx + (qt << 7) + wv * 16 + r15);
        #pragma unroll
        for (int kk = 0; kk < 2; ++kk)
            qf[kk] = *(const short8*)&qhat[qrow * Ex + h * Dx + kk * 32 + g * 8];
    }

    // staging: wave wv stages rows [wv*8, wv*8+8) of the 64-row tile (1 load)
    auto stageK = [&](int kt, int buf) {
        int row = wv * 8 + lrow;
        gload16(&khat[(size_t)(b * Sx + (kt << 6) + row) * Ex + h * Dx + ((lgi ^ (row & 7)) << 3)],
                &ks[buf][(wv * 8) * 64]);
    };
    auto stageV = [&](int kt, int buf) {
        int row = wv * 8 + lrow;
        gload16(&vT[((size_t)bh * Dx + row) * Sx + (kt << 6) + ((lgi ^ (row & 7)) << 3)],
                &vs[buf][(wv * 8) * 64]);
    };

    float sr = 0.f;
    const int qg0 = (qt << 7) + wv * 16 + r15;

    // ---- pass 1: 3-buf counted-vmcnt pipeline (K only) ----
    stageK(0, 0);
    if (nkt > 1) stageK(1, 1);
    __syncthreads();                 // full drain: bl init + stage(0) visible
    for (int kt = 0; kt < nkt; ++kt) {
        if (kt) {
            if (kt + 1 < nkt) asm volatile("s_waitcnt vmcnt(1)" ::: "memory");
            else              asm volatile("s_waitcnt vmcnt(0)" ::: "memory");
            __builtin_amdgcn_s_barrier();
            __builtin_amdgcn_sched_barrier(0);
        }
        if (kt + 2 < nkt) stageK(kt + 2, (kt + 2) % 3);
        const short* kb = ks[kt % 3];
        f32x4 sf[4] = {};
        __builtin_amdgcn_s_setprio(1);
        #pragma unroll
        for (int kk = 0; kk < 64; kk += 32) {
            const int sw = (((kk >> 3) + g) ^ (r15 & 7)) << 3;
            short8 a[4];
            #pragma unroll
            for (int m = 0; m < 4; ++m) a[m] = *(const short8*)&kb[(m * 16 + r15) * 64 + sw];
            #pragma unroll
            for (int m = 0; m < 4; ++m)
                sf[m] = __builtin_amdgcn_mfma_f32_16x16x32_bf16(a[m], qf[kk >> 5], sf[m], 0, 0, 0);
        }
        __builtin_amdgcn_s_setprio(0);
        const int kcb = (kt << 6) + (g << 2);
        int base = qg0 + 512 - kcb;
        float psum = 0.f;
        #pragma unroll
        for (int m = 0; m < 4; ++m) {
            int b0 = base - m * 16;
            #pragma unroll
            for (int r = 0; r < 4; ++r) {
                int idx = b0 - r;            // >= 385 always
                idx = idx > 1024 ? 1024 : idx;
                psum += exp2fast(fmaf(sf[m][r], cs2, bl[idx]));
            }
        }
        psum += __shfl_xor(psum, 16);
        psum += __shfl_xor(psum, 32);
        sr += psum;
    }

    const float inv = 1.0f / sr;
    f32x4 of[4] = {};
    float* Ap = attn + (size_t)bh * ((size_t)Sx * Sx);

    // ---- pass 2: counted-vmcnt pipeline; nt stores never drained ----
    __syncthreads();                 // pass-1 reads done before restaging
    stageK(0, 0); stageV(0, 0);
    if (nkt > 1) { stageK(1, 1); stageV(1, 1); }
    if (nkt > 1) asm volatile("s_waitcnt vmcnt(2)" ::: "memory");
    else         asm volatile("s_waitcnt vmcnt(0)" ::: "memory");
    __builtin_amdgcn_s_barrier();
    __builtin_amdgcn_sched_barrier(0);

    for (int kt = 0; kt < nkt; ++kt) {
        if (kt >= 1) {
            // wait for own stage(kt); allow stores(kt-2), stage(kt+1), stores(kt-1)
            if (kt >= 2 && kt + 1 < nkt)      asm volatile("s_waitcnt vmcnt(10)" ::: "memory");
            else if (kt >= 2)                 asm volatile("s_waitcnt vmcnt(8)" ::: "memory");
            else if (kt + 1 < nkt)            asm volatile("s_waitcnt vmcnt(6)" ::: "memory");
            else                              asm volatile("s_waitcnt vmcnt(4)" ::: "memory");
            __builtin_amdgcn_s_barrier();
            __builtin_amdgcn_sched_barrier(0);
        }
        const int cur = kt % 3;
        f32x4 sf[4] = {};
        __builtin_amdgcn_s_setprio(1);
        #pragma unroll
        for (int kk = 0; kk < 64; kk += 32) {
            const int sw = (((kk >> 3) + g) ^ (r15 & 7)) << 3;
            short8 a[4];
            #pragma unroll
            for (int m = 0; m < 4; ++m) a[m] = *(const short8*)&ks[cur][(m * 16 + r15) * 64 + sw];
            #pragma unroll
            for (int m = 0; m < 4; ++m)
                sf[m] = __builtin_amdgcn_mfma_f32_16x16x32_bf16(a[m], qf[kk >> 5], sf[m], 0, 0, 0);
        }
        __builtin_amdgcn_s_setprio(0);
        if (kt + 2 < nkt) { stageK(kt + 2, (kt + 2) % 3); stageV(kt + 2, (kt + 2) % 3); }
        {
            const int q = qg0;
            const int qrow = wv * 16 + r15;
            #pragma unroll
            for (int m = 0; m < 4; ++m) {
                int kc0 = (kt << 6) + m * 16 + (g << 2);
                int b0 = q + 512 - kc0;
                f32x4 pv;
                #pragma unroll
                for (int r = 0; r < 4; ++r) {
                    int idx = b0 - r;
                    idx = idx > 1024 ? 1024 : idx;
                    pv[r] = exp2fast(fmaf(sf[m][r], cs2, bl[idx])) * inv;
                }
                __builtin_nontemporal_store(pv, (f32x4*)&Ap[(size_t)q * Sx + kc0]);
                u32x2 pk;
                pk[0] = cvtpk_bf16(pv[0], pv[1]);
                pk[1] = cvtpk_bf16(pv[2], pv[3]);
                int gphys = (m * 2 + (g >> 1)) ^ (r15 & 7);
                *(u32x2*)&ps[qrow * 64 + gphys * 8 + (g & 1) * 4] = pk;
            }
        }
        // ps rows are wave-private: no barrier needed (lgkmcnt RAW only)
        __builtin_amdgcn_s_setprio(1);
        #pragma unroll
        for (int kk = 0; kk < 64; kk += 32) {
            const int sw = (((kk >> 3) + g) ^ (r15 & 7)) << 3;
            short8 a[4], bp;
            #pragma unroll
            for (int m = 0; m < 4; ++m) a[m] = *(const short8*)&vs[cur][(m * 16 + r15) * 64 + sw];
            bp = *(const short8*)&ps[(wv * 16 + r15) * 64 + sw];
            #pragma unroll
            for (int m = 0; m < 4; ++m)
                of[m] = __builtin_amdgcn_mfma_f32_16x16x32_bf16(a[m], bp, of[m], 0, 0, 0);
        }
        __builtin_amdgcn_s_setprio(0);
    }

    // O^T C-layout: col = q (r15), rows = d 4-contig -> 8B stores
    {
        const int qv = (qt << 7) + wv * 16 + r15;
        #pragma unroll
        for (int m = 0; m < 4; ++m) {
            int d0 = m * 16 + (g << 2);
            u32x2 s;
            s[0] = cvtpk_bf16(of[m][0], of[m][1]);
            s[1] = cvtpk_bf16(of[m][2], of[m][3]);
            *(u32x2*)&om[(size_t)(b * Sx + qv) * Ex + h * Dx + d0] = s;
        }
    }

    // zero-fill fully masked region (nontemporal), 512 threads
    const int c0 = nkt << 6;
    f32x4 z = {0.f, 0.f, 0.f, 0.f};
    for (int row = tid >> 3; row < 128; row += 64) {
        size_t base = (size_t)((qt << 7) + row) * Sx;
        for (int c = c0 + ((tid & 7) << 2); c < Sx; c += 32)
            __builtin_nontemporal_store(z, (f32x4*)&Ap[base + c]);
    }
}

extern "C" void kernel_launch(void* const* d_in, const int* in_sizes, int n_in,
                              void* d_out, int out_size, void* d_ws, size_t ws_size,
                              hipStream_t stream) {
    const float* query = (const float*)d_in[0];
    const float* key   = (const float*)d_in[1];
    const float* value = (const float*)d_in[2];
    const float* bq = (const float*)d_in[4];
    const float* bk = (const float*)d_in[6];
    const float* bv = (const float*)d_in[8];
    const float* bo = (const float*)d_in[10];
    const float* Wq = (const float*)d_in[3];
    const float* Wk = (const float*)d_in[5];
    const float* Wv = (const float*)d_in[7];
    const float* Wo = (const float*)d_in[9];
    const float* tbl = (const float*)d_in[11];

    short* ws = (short*)d_ws;
    short* qx  = ws;                    // query bf16; later reused as O (bf16)
    short* wob = ws + 15728640;
    short* qh  = ws + 16777216;
    short* kh  = ws + 20971520;
    short* vt  = ws + 25165824;

    float* outp  = (float*)d_out;
    float* attnp = outp + 4194304;

    prep<<<dim3(1024, 7), 256, 0, stream>>>(query, key, value, Wq, Wk, Wv, Wo, ws);
    gemm_qkv3<<<dim3(32, 8, 3), 256, 0, stream>>>(ws, bq, bk, bv, qh, kh, vt);
    attn_fused<<<dim3(16, 32), 512, 0, stream>>>(qh, kh, vt, tbl, attnp, qx);
    gemm_out<<<dim3(32, 8), 256, 0, stream>>>(qx, wob, bo, outp);
}

// Round 14
// 223.170 us; speedup vs baseline: 1.2356x; 1.2319x over previous
//
#include <hip/hip_runtime.h>
#include <hip/hip_bf16.h>
#include <stdint.h>

#define Sx 2048
#define Ex 1024
#define Hx 16
#define Dx 64

typedef __attribute__((ext_vector_type(8))) short short8;
typedef __attribute__((ext_vector_type(4))) short bh4;
typedef __attribute__((ext_vector_type(4))) float f32x4;
typedef __attribute__((ext_vector_type(2))) unsigned int u32x2;

// fp32 -> bf16 bits, round-to-nearest-even
__device__ inline short f2bf(float f) {
    unsigned u = __builtin_bit_cast(unsigned, f);
    u = (u + 0x7fffu + ((u >> 16) & 1u)) >> 16;
    return (short)u;
}

// packed pair fp32 -> 2x bf16 in one u32 (lo = a, hi = b)
__device__ inline unsigned cvtpk_bf16(float a, float b) {
    unsigned r;
    asm("v_cvt_pk_bf16_f32 %0, %1, %2" : "=v"(r) : "v"(a), "v"(b));
    return r;
}

// fast 2^x (v_exp_f32)
__device__ inline float exp2fast(float x) { return __builtin_amdgcn_exp2f(x); }

// async global->LDS, 16B per lane; LDS base wave-uniform, HW adds lane*16.
__device__ inline void gload16(const short* g, short* l) {
    __builtin_amdgcn_global_load_lds((const __attribute__((address_space(1))) void*)g,
                                     (__attribute__((address_space(3))) void*)l, 16, 0, 0);
}

// ---------------------------------------------------------------------------
// prep: convert the 3 activations + 4 weights fp32 -> bf16 into ws
// ---------------------------------------------------------------------------
__global__ __launch_bounds__(256) void prep(const float* __restrict__ q,
                                            const float* __restrict__ k,
                                            const float* __restrict__ v,
                                            const float* __restrict__ wq,
                                            const float* __restrict__ wk,
                                            const float* __restrict__ wv_,
                                            const float* __restrict__ wo,
                                            short* __restrict__ ws) {
    const int seg = blockIdx.y;
    const float* src; size_t n, doff;
    switch (seg) {
        case 0: src = q;   n = 4194304; doff = 0;        break;
        case 1: src = k;   n = 4194304; doff = 4194304;  break;
        case 2: src = v;   n = 4194304; doff = 8388608;  break;
        case 3: src = wq;  n = 1048576; doff = 12582912; break;
        case 4: src = wk;  n = 1048576; doff = 13631488; break;
        case 5: src = wv_; n = 1048576; doff = 14680064; break;
        default: src = wo; n = 1048576; doff = 15728640; break;
    }
    short* dst = ws + doff;
    for (size_t i = ((size_t)blockIdx.x * 256 + threadIdx.x) * 8; i < n;
         i += (size_t)gridDim.x * 256 * 8) {
        float4 f0 = *(const float4*)&src[i];
        float4 f1 = *(const float4*)&src[i + 4];
        short8 s;
        s[0]=f2bf(f0.x); s[1]=f2bf(f0.y); s[2]=f2bf(f0.z); s[3]=f2bf(f0.w);
        s[4]=f2bf(f1.x); s[5]=f2bf(f1.y); s[6]=f2bf(f1.z); s[7]=f2bf(f1.w);
        *(short8*)&dst[i] = s;
    }
}

// ---------------------------------------------------------------------------
// Merged QKV projection: grid.z selects (X, W, bias, out, mode).
// z=0,1: qhat/khat [b,s,e] bf16 (D transposed). z=2: vT [b,h,d,s] bf16.
// ---------------------------------------------------------------------------
__global__ __launch_bounds__(256) void gemm_qkv3(const short* __restrict__ wsb,
                                                 const float* __restrict__ bq,
                                                 const float* __restrict__ bk,
                                                 const float* __restrict__ bv,
                                                 short* __restrict__ qh,
                                                 short* __restrict__ kh,
                                                 short* __restrict__ vt) {
    __shared__ short wt[128 * 64];
    __shared__ short xt[128 * 64];
    const int z = blockIdx.z;
    const short* X  = wsb + (size_t)z * 4194304;
    const short* Wm = wsb + 12582912 + (size_t)z * 1048576;
    const float* bias = (z == 0) ? bq : (z == 1) ? bk : bv;
    short* outb = (z == 0) ? qh : (z == 1) ? kh : vt;
    const bool vmode = (z == 2);

    const int tid = threadIdx.x;
    const int l = tid & 63, wv = tid >> 6;
    const int r15 = l & 15, g = l >> 4;
    const int wm = wv >> 1, wn = wv & 1;
    const int i0 = blockIdx.x << 7;
    const int j0 = blockIdx.y << 7;
    const int lrow = l >> 3, lgi = l & 7;

    f32x4 acc[4][4] = {};

    for (int k0 = 0; k0 < Ex; k0 += 64) {
        __syncthreads();
        #pragma unroll
        for (int p = 0; p < 4; ++p) {
            int row = p * 32 + wv * 8 + lrow;
            int col = ((lgi ^ (row & 7)) << 3) + k0;
            gload16(&Wm[(size_t)(j0 + row) * Ex + col], &wt[(p * 32 + wv * 8) * 64]);
            gload16(&X [(size_t)(i0 + row) * Ex + col], &xt[(p * 32 + wv * 8) * 64]);
        }
        __syncthreads();
        const short* At = vmode ? xt : wt;
        const short* Bt = vmode ? wt : xt;
        #pragma unroll
        for (int kk = 0; kk < 64; kk += 32) {
            const int sw = (((kk >> 3) + g) ^ (r15 & 7)) << 3;
            short8 a[4], b[4];
            #pragma unroll
            for (int m = 0; m < 4; ++m)
                a[m] = *(const short8*)&At[(wm * 64 + m * 16 + r15) * 64 + sw];
            #pragma unroll
            for (int n = 0; n < 4; ++n)
                b[n] = *(const short8*)&Bt[(wn * 64 + n * 16 + r15) * 64 + sw];
            #pragma unroll
            for (int m = 0; m < 4; ++m)
                #pragma unroll
                for (int n = 0; n < 4; ++n)
                    acc[m][n] = __builtin_amdgcn_mfma_f32_16x16x32_bf16(a[m], b[n], acc[m][n], 0, 0, 0);
        }
    }

    if (!vmode) {              // D[j][i]; rows j 4-contig per lane
        #pragma unroll
        for (int m = 0; m < 4; ++m) {
            int jb = j0 + wm * 64 + m * 16 + (g << 2);
            float4 bvv = *(const float4*)&bias[jb];
            #pragma unroll
            for (int n = 0; n < 4; ++n) {
                int i = i0 + wn * 64 + n * 16 + r15;
                bh4 s;
                s[0] = f2bf(acc[m][n][0] + bvv.x);
                s[1] = f2bf(acc[m][n][1] + bvv.y);
                s[2] = f2bf(acc[m][n][2] + bvv.z);
                s[3] = f2bf(acc[m][n][3] + bvv.w);
                *(bh4*)&outb[(size_t)i * Ex + jb] = s;
            }
        }
    } else {                   // D[i][j]; rows i 4-contig -> vT[b,h,d,s]
        #pragma unroll
        for (int m = 0; m < 4; ++m) {
            int ib = i0 + wm * 64 + m * 16 + (g << 2);
            int b_ = ib >> 11, s0 = ib & 2047;
            #pragma unroll
            for (int n = 0; n < 4; ++n) {
                int j = j0 + wn * 64 + n * 16 + r15;
                float bj = bias[j];
                bh4 s;
                s[0] = f2bf(acc[m][n][0] + bj);
                s[1] = f2bf(acc[m][n][1] + bj);
                s[2] = f2bf(acc[m][n][2] + bj);
                s[3] = f2bf(acc[m][n][3] + bj);
                *(bh4*)&outb[((size_t)(b_ * Hx + (j >> 6)) * Dx + (j & 63)) * Sx + s0] = s;
            }
        }
    }
}

// ---------------------------------------------------------------------------
// Output projection: fp32 out = Xb(bf16) @ W^T + bias. 2-phase LDS dbuf.
// ---------------------------------------------------------------------------
__global__ __launch_bounds__(256) void gemm_out(const short* __restrict__ Xb,
                                                const short* __restrict__ Wb,
                                                const float* __restrict__ bias,
                                                float* __restrict__ out) {
    __shared__ short wt[2][128 * 64];
    __shared__ short xt[2][128 * 64];
    const int tid = threadIdx.x;
    const int l = tid & 63, wv = tid >> 6;
    const int r15 = l & 15, g = l >> 4;
    const int wm = wv >> 1, wn = wv & 1;
    const int i0 = blockIdx.x << 7;
    const int j0 = blockIdx.y << 7;
    const int lrow = l >> 3, lgi = l & 7;

    f32x4 acc[4][4] = {};

    auto stage = [&](int it, int buf) {
        int k0 = it << 6;
        #pragma unroll
        for (int p = 0; p < 4; ++p) {
            int row = p * 32 + wv * 8 + lrow;
            int col = ((lgi ^ (row & 7)) << 3) + k0;
            gload16(&Wb[(size_t)(j0 + row) * Ex + col], &wt[buf][(p * 32 + wv * 8) * 64]);
            gload16(&Xb[(size_t)(i0 + row) * Ex + col], &xt[buf][(p * 32 + wv * 8) * 64]);
        }
    };

    stage(0, 0);
    for (int it = 0; it < 16; ++it) {
        __syncthreads();
        if (it + 1 < 16) stage(it + 1, (it + 1) & 1);
        const int cur = it & 1;
        #pragma unroll
        for (int kk = 0; kk < 64; kk += 32) {
            const int sw = (((kk >> 3) + g) ^ (r15 & 7)) << 3;
            short8 a[4], b[4];
            #pragma unroll
            for (int m = 0; m < 4; ++m)
                a[m] = *(const short8*)&wt[cur][(wm * 64 + m * 16 + r15) * 64 + sw];
            #pragma unroll
            for (int n = 0; n < 4; ++n)
                b[n] = *(const short8*)&xt[cur][(wn * 64 + n * 16 + r15) * 64 + sw];
            #pragma unroll
            for (int m = 0; m < 4; ++m)
                #pragma unroll
                for (int n = 0; n < 4; ++n)
                    acc[m][n] = __builtin_amdgcn_mfma_f32_16x16x32_bf16(a[m], b[n], acc[m][n], 0, 0, 0);
        }
    }

    #pragma unroll
    for (int m = 0; m < 4; ++m) {
        int jb = j0 + wm * 64 + m * 16 + (g << 2);
        float4 bvv = *(const float4*)&bias[jb];
        #pragma unroll
        for (int n = 0; n < 4; ++n) {
            int i = i0 + wn * 64 + n * 16 + r15;
            float4 o;
            o.x = acc[m][n][0] + bvv.x;
            o.y = acc[m][n][1] + bvv.y;
            o.z = acc[m][n][2] + bvv.z;
            o.w = acc[m][n][3] + bvv.w;
            *(float4*)&out[(size_t)i * Ex + jb] = o;
        }
    }
}

// ---------------------------------------------------------------------------
// Fused causal attention — 8-wave blocks. NEW: no scattered fp32 P stores.
// P (normalized bf16) lives in double-buffered ps; a bulk phase per tile
// reads ps back (inverse XOR layout: slot = (kc>>3) ^ (row&7)), expands
// bf16->fp32 by bit-shift, and streams attn out DENSE (256B/row/instr).
// K/V: 2-buffer + plain __syncthreads (counted-vmcnt proven value-less).
// ---------------------------------------------------------------------------
__global__ void attn_fused(const short* __restrict__ qhat,
                           const short* __restrict__ khat,
                           const short* __restrict__ vT,
                           const float* __restrict__ table,
                           float* __restrict__ attn,
                           short* __restrict__ om) {
    __shared__ short ks[2][64 * 64];
    __shared__ short vs[2][64 * 64];
    __shared__ short ps[2][128 * 64];
    __shared__ float bl[1028];

    const int tid = threadIdx.x;
    const int l = tid & 63, wv = tid >> 6;       // wv in [0,8)
    const int r15 = l & 15, g = l >> 4;

    // block swizzle: same-bh blocks on one XCD; co-resident pairs (qt,15-qt)
    const int lin = blockIdx.x + (blockIdx.y << 4);
    const int xcd = lin & 7, slot = lin >> 3;
    const int bh = xcd + ((slot & 3) << 3);
    const int qidx = (slot >> 2) & 7;
    const int qt = (slot >> 5) ? (15 - qidx) : qidx;

    const int b = bh >> 4, h = bh & 15;
    const int lrow = l >> 3, lgi = l & 7;
    const int nkt = 2 * qt + 2;
    const float cs2 = 0.18033688f;   // 0.125 * log2(e)

    for (int i = tid; i < 1025; i += 512)
        bl[i] = (i < 512) ? -3e30f : (table[i * Hx + h] - 16.0f) * 1.4426950408889634f;

    // Q fragments in registers: wave owns q rows [qt*128 + wv*16, +16)
    short8 qf[2];
    {
        const size_t qrow = (size_t)(b * Sx + (qt << 7) + wv * 16 + r15);
        #pragma unroll
        for (int kk = 0; kk < 2; ++kk)
            qf[kk] = *(const short8*)&qhat[qrow * Ex + h * Dx + kk * 32 + g * 8];
    }

    // staging: wave wv stages rows [wv*8, wv*8+8) of the 64-row tile (1 load)
    auto stageK = [&](int kt, int buf) {
        int row = wv * 8 + lrow;
        gload16(&khat[(size_t)(b * Sx + (kt << 6) + row) * Ex + h * Dx + ((lgi ^ (row & 7)) << 3)],
                &ks[buf][(wv * 8) * 64]);
    };
    auto stageV = [&](int kt, int buf) {
        int row = wv * 8 + lrow;
        gload16(&vT[((size_t)bh * Dx + row) * Sx + (kt << 6) + ((lgi ^ (row & 7)) << 3)],
                &vs[buf][(wv * 8) * 64]);
    };

    float sr = 0.f;
    const int qg0 = (qt << 7) + wv * 16 + r15;

    // ---- pass 1: row sum of exp2(s*cs2 + bl), 2-buf K staging ----
    stageK(0, 0);
    for (int kt = 0; kt < nkt; ++kt) {
        __syncthreads();                 // covers bl init + stage(kt)
        if (kt + 1 < nkt) stageK(kt + 1, (kt + 1) & 1);
        const short* kb = ks[kt & 1];
        f32x4 sf[4] = {};
        __builtin_amdgcn_s_setprio(1);
        #pragma unroll
        for (int kk = 0; kk < 64; kk += 32) {
            const int sw = (((kk >> 3) + g) ^ (r15 & 7)) << 3;
            short8 a[4];
            #pragma unroll
            for (int m = 0; m < 4; ++m) a[m] = *(const short8*)&kb[(m * 16 + r15) * 64 + sw];
            #pragma unroll
            for (int m = 0; m < 4; ++m)
                sf[m] = __builtin_amdgcn_mfma_f32_16x16x32_bf16(a[m], qf[kk >> 5], sf[m], 0, 0, 0);
        }
        __builtin_amdgcn_s_setprio(0);
        const int kcb = (kt << 6) + (g << 2);
        int base = qg0 + 512 - kcb;
        float psum = 0.f;
        #pragma unroll
        for (int m = 0; m < 4; ++m) {
            int b0 = base - m * 16;
            #pragma unroll
            for (int r = 0; r < 4; ++r) {
                int idx = b0 - r;            // >= 385 always
                idx = idx > 1024 ? 1024 : idx;
                psum += exp2fast(fmaf(sf[m][r], cs2, bl[idx]));
            }
        }
        psum += __shfl_xor(psum, 16);
        psum += __shfl_xor(psum, 32);
        sr += psum;
    }

    const float inv = 1.0f / sr;
    f32x4 of[4] = {};
    float* Ap = attn + (size_t)bh * ((size_t)Sx * Sx);

    // bulk writer: tile t -> dense fp32 stores from ps[t&1]
    auto bulk_store = [&](int t) {
        const short* pb = ps[t & 1];
        const int j2 = tid & 15;         // 4 fp32 cols per thread
        int row = tid >> 4;              // 0..31, 4 passes
        #pragma unroll
        for (int h2 = 0; h2 < 4; ++h2, row += 32) {
            bh4 v = *(const bh4*)&pb[row * 64 + (((j2 >> 1) ^ (row & 7)) << 3) + (j2 & 1) * 4];
            f32x4 o;
            #pragma unroll
            for (int r = 0; r < 4; ++r)
                o[r] = __builtin_bit_cast(float, (unsigned)((unsigned short)v[r]) << 16);
            __builtin_nontemporal_store(o, (f32x4*)&Ap[(size_t)((qt << 7) + row) * Sx + (t << 6) + j2 * 4]);
        }
    };

    // ---- pass 2: recompute, ps (dbuf) -> PV + deferred dense attn store ----
    __syncthreads();
    stageK(0, 0); stageV(0, 0);
    for (int kt = 0; kt < nkt; ++kt) {
        __syncthreads();                 // publishes ks/vs(kt) and ps(kt-1)
        if (kt + 1 < nkt) { stageK(kt + 1, (kt + 1) & 1); stageV(kt + 1, (kt + 1) & 1); }
        if (kt > 0) bulk_store(kt - 1);
        const int cur = kt & 1;
        f32x4 sf[4] = {};
        __builtin_amdgcn_s_setprio(1);
        #pragma unroll
        for (int kk = 0; kk < 64; kk += 32) {
            const int sw = (((kk >> 3) + g) ^ (r15 & 7)) << 3;
            short8 a[4];
            #pragma unroll
            for (int m = 0; m < 4; ++m) a[m] = *(const short8*)&ks[cur][(m * 16 + r15) * 64 + sw];
            #pragma unroll
            for (int m = 0; m < 4; ++m)
                sf[m] = __builtin_amdgcn_mfma_f32_16x16x32_bf16(a[m], qf[kk >> 5], sf[m], 0, 0, 0);
        }
        __builtin_amdgcn_s_setprio(0);
        {
            const int qrow = wv * 16 + r15;
            short* pw = ps[cur];
            #pragma unroll
            for (int m = 0; m < 4; ++m) {
                int kc0 = (kt << 6) + m * 16 + (g << 2);
                int b0 = qg0 + 512 - kc0;
                float pv0, pv1, pv2, pv3;
                {
                    int i0_ = b0;     i0_ = i0_ > 1024 ? 1024 : i0_;
                    int i1_ = b0 - 1; i1_ = i1_ > 1024 ? 1024 : i1_;
                    int i2_ = b0 - 2; i2_ = i2_ > 1024 ? 1024 : i2_;
                    int i3_ = b0 - 3; i3_ = i3_ > 1024 ? 1024 : i3_;
                    pv0 = exp2fast(fmaf(sf[m][0], cs2, bl[i0_])) * inv;
                    pv1 = exp2fast(fmaf(sf[m][1], cs2, bl[i1_])) * inv;
                    pv2 = exp2fast(fmaf(sf[m][2], cs2, bl[i2_])) * inv;
                    pv3 = exp2fast(fmaf(sf[m][3], cs2, bl[i3_])) * inv;
                }
                u32x2 pk;
                pk[0] = cvtpk_bf16(pv0, pv1);
                pk[1] = cvtpk_bf16(pv2, pv3);
                int gphys = (m * 2 + (g >> 1)) ^ (r15 & 7);
                *(u32x2*)&pw[qrow * 64 + gphys * 8 + (g & 1) * 4] = pk;
            }
        }
        // ps rows are wave-private for PV: no barrier needed (lgkmcnt RAW only)
        __builtin_amdgcn_s_setprio(1);
        #pragma unroll
        for (int kk = 0; kk < 64; kk += 32) {
            const int sw = (((kk >> 3) + g) ^ (r15 & 7)) << 3;
            short8 a[4], bp;
            #pragma unroll
            for (int m = 0; m < 4; ++m) a[m] = *(const short8*)&vs[cur][(m * 16 + r15) * 64 + sw];
            bp = *(const short8*)&ps[cur][(wv * 16 + r15) * 64 + sw];
            #pragma unroll
            for (int m = 0; m < 4; ++m)
                of[m] = __builtin_amdgcn_mfma_f32_16x16x32_bf16(a[m], bp, of[m], 0, 0, 0);
        }
        __builtin_amdgcn_s_setprio(0);
    }
    __syncthreads();                     // publish last tile's ps
    bulk_store(nkt - 1);

    // O^T C-layout: col = q (r15), rows = d 4-contig -> 8B stores
    {
        const int qv = (qt << 7) + wv * 16 + r15;
        #pragma unroll
        for (int m = 0; m < 4; ++m) {
            int d0 = m * 16 + (g << 2);
            u32x2 s;
            s[0] = cvtpk_bf16(of[m][0], of[m][1]);
            s[1] = cvtpk_bf16(of[m][2], of[m][3]);
            *(u32x2*)&om[(size_t)(b * Sx + qv) * Ex + h * Dx + d0] = s;
        }
    }

    // zero-fill fully masked region (nontemporal), 512 threads
    const int c0 = nkt << 6;
    f32x4 z = {0.f, 0.f, 0.f, 0.f};
    for (int row = tid >> 3; row < 128; row += 64) {
        size_t base = (size_t)((qt << 7) + row) * Sx;
        for (int c = c0 + ((tid & 7) << 2); c < Sx; c += 32)
            __builtin_nontemporal_store(z, (f32x4*)&Ap[base + c]);
    }
}

extern "C" void kernel_launch(void* const* d_in, const int* in_sizes, int n_in,
                              void* d_out, int out_size, void* d_ws, size_t ws_size,
                              hipStream_t stream) {
    const float* query = (const float*)d_in[0];
    const float* key   = (const float*)d_in[1];
    const float* value = (const float*)d_in[2];
    const float* bq = (const float*)d_in[4];
    const float* bk = (const float*)d_in[6];
    const float* bv = (const float*)d_in[8];
    const float* bo = (const float*)d_in[10];
    const float* Wq = (const float*)d_in[3];
    const float* Wk = (const float*)d_in[5];
    const float* Wv = (const float*)d_in[7];
    const float* Wo = (const float*)d_in[9];
    const float* tbl = (const float*)d_in[11];

    short* ws = (short*)d_ws;
    short* qx  = ws;                    // query bf16; later reused as O (bf16)
    short* wob = ws + 15728640;
    short* qh  = ws + 16777216;
    short* kh  = ws + 20971520;
    short* vt  = ws + 25165824;

    float* outp  = (float*)d_out;
    float* attnp = outp + 4194304;

    prep<<<dim3(1024, 7), 256, 0, stream>>>(query, key, value, Wq, Wk, Wv, Wo, ws);
    gemm_qkv3<<<dim3(32, 8, 3), 256, 0, stream>>>(ws, bq, bk, bv, qh, kh, vt);
    attn_fused<<<dim3(16, 32), 512, 0, stream>>>(qh, kh, vt, tbl, attnp, qx);
    gemm_out<<<dim3(32, 8), 256, 0, stream>>>(qx, wob, bo, outp);
}